// Round 1
// baseline (5901.235 us; speedup 1.0000x reference)
//
#include <hip/hip_runtime.h>
#include <math.h>

// ---------------------------------------------------------------------------
// MPConv: per-edge MLP (160->64, LN+GELU, 64->64) + scatter-add to target node
// Round 0: thread-per-edge, fp32 VALU, uniform (scalar-load) weights,
//          hardware f32 atomics for the scatter.
// ---------------------------------------------------------------------------

#define CAT_DIM 160
#define OUT_CH 64

// acc[c4] += f * w_row[c4] for the 16 float4 chunks of one 64-wide weight row
static __device__ __forceinline__ void fma_row(float4* acc,
                                               const float4* __restrict__ w,
                                               float f) {
#pragma unroll
    for (int c = 0; c < 16; c++) {
        float4 wv = w[c];
        acc[c].x = fmaf(f, wv.x, acc[c].x);
        acc[c].y = fmaf(f, wv.y, acc[c].y);
        acc[c].z = fmaf(f, wv.z, acc[c].z);
        acc[c].w = fmaf(f, wv.w, acc[c].w);
    }
}

__global__ __launch_bounds__(256) void mpconv_edge_kernel(
    const float* __restrict__ x,      // [N,64]
    const int*   __restrict__ ei,     // [2,E]
    const float* __restrict__ ea,     // [E,32]
    const float* __restrict__ W1,     // [160,64] row-major (k,c)
    const float* __restrict__ b1,     // [64]
    const float* __restrict__ gam,    // [64]
    const float* __restrict__ bet,    // [64]
    const float* __restrict__ W2,     // [64,64]
    const float* __restrict__ b2,     // [64]
    float*       __restrict__ out,    // [N,64]
    int E)
{
    int e = blockIdx.x * blockDim.x + threadIdx.x;
    if (e >= E) return;

    const int i = ei[e];        // source (x[i] is first 64 of concat)
    const int j = ei[E + e];    // target (x[j] second 64; scatter dest)

    const float4* __restrict__ W1_4 = (const float4*)W1;  // [160][16]
    const float4* __restrict__ b1_4 = (const float4*)b1;

    float4 acc[16];
#pragma unroll
    for (int c = 0; c < 16; c++) acc[c] = b1_4[c];

    const float4* __restrict__ xi = (const float4*)(x + (size_t)i * 64);
    const float4* __restrict__ xj = (const float4*)(x + (size_t)j * 64);
    const float4* __restrict__ ev = (const float4*)(ea + (size_t)e * 32);

    // ---- GEMM1: rows 0..63 (x[i]) -------------------------------------
#pragma unroll 1
    for (int k4 = 0; k4 < 16; k4++) {
        float4 f = xi[k4];
        const float4* w = W1_4 + (4 * k4) * 16;
        fma_row(acc, w,      f.x);
        fma_row(acc, w + 16, f.y);
        fma_row(acc, w + 32, f.z);
        fma_row(acc, w + 48, f.w);
    }
    // ---- rows 64..127 (x[j]) ------------------------------------------
#pragma unroll 1
    for (int k4 = 0; k4 < 16; k4++) {
        float4 f = xj[k4];
        const float4* w = W1_4 + (64 + 4 * k4) * 16;
        fma_row(acc, w,      f.x);
        fma_row(acc, w + 16, f.y);
        fma_row(acc, w + 32, f.z);
        fma_row(acc, w + 48, f.w);
    }
    // ---- rows 128..159 (edge_attr) ------------------------------------
#pragma unroll 1
    for (int k4 = 0; k4 < 8; k4++) {
        float4 f = ev[k4];
        const float4* w = W1_4 + (128 + 4 * k4) * 16;
        fma_row(acc, w,      f.x);
        fma_row(acc, w + 16, f.y);
        fma_row(acc, w + 32, f.z);
        fma_row(acc, w + 48, f.w);
    }

    // ---- LayerNorm (biased var, eps inside rsqrt) + exact GELU --------
    float mu = 0.f;
#pragma unroll
    for (int c = 0; c < 16; c++)
        mu += acc[c].x + acc[c].y + acc[c].z + acc[c].w;
    mu *= (1.0f / 64.0f);

    float var = 0.f;
#pragma unroll
    for (int c = 0; c < 16; c++) {
        float dx = acc[c].x - mu, dy = acc[c].y - mu;
        float dz = acc[c].z - mu, dw = acc[c].w - mu;
        var += dx * dx + dy * dy + dz * dz + dw * dw;
    }
    var *= (1.0f / 64.0f);
    const float inv = rsqrtf(var + 1e-5f);

    const float4* __restrict__ g4 = (const float4*)gam;
    const float4* __restrict__ be4 = (const float4*)bet;
#pragma unroll
    for (int c = 0; c < 16; c++) {
        float4 g = g4[c], b = be4[c];
        float hx = (acc[c].x - mu) * inv * g.x + b.x;
        float hy = (acc[c].y - mu) * inv * g.y + b.y;
        float hz = (acc[c].z - mu) * inv * g.z + b.z;
        float hw = (acc[c].w - mu) * inv * g.w + b.w;
        // exact GELU: 0.5*h*(1+erf(h/sqrt(2)))
        acc[c].x = 0.5f * hx * (1.0f + erff(hx * 0.70710678118654752f));
        acc[c].y = 0.5f * hy * (1.0f + erff(hy * 0.70710678118654752f));
        acc[c].z = 0.5f * hz * (1.0f + erff(hz * 0.70710678118654752f));
        acc[c].w = 0.5f * hw * (1.0f + erff(hw * 0.70710678118654752f));
    }

    // ---- GEMM2: m = h @ W2 + b2 ---------------------------------------
    const float4* __restrict__ W2_4 = (const float4*)W2;  // [64][16]
    const float4* __restrict__ b2_4 = (const float4*)b2;
    float4 m[16];
#pragma unroll
    for (int c = 0; c < 16; c++) m[c] = b2_4[c];

#pragma unroll
    for (int k4 = 0; k4 < 16; k4++) {   // must unroll: static index into acc[]
        float4 hk = acc[k4];
        const float4* w = W2_4 + (4 * k4) * 16;
        fma_row(m, w,      hk.x);
        fma_row(m, w + 16, hk.y);
        fma_row(m, w + 32, hk.z);
        fma_row(m, w + 48, hk.w);
    }

    // ---- scatter-add onto target node j -------------------------------
    float* op = out + (size_t)j * 64;
#pragma unroll
    for (int c = 0; c < 16; c++) {
        unsafeAtomicAdd(op + 4 * c + 0, m[c].x);
        unsafeAtomicAdd(op + 4 * c + 1, m[c].y);
        unsafeAtomicAdd(op + 4 * c + 2, m[c].z);
        unsafeAtomicAdd(op + 4 * c + 3, m[c].w);
    }
}

extern "C" void kernel_launch(void* const* d_in, const int* in_sizes, int n_in,
                              void* d_out, int out_size, void* d_ws, size_t ws_size,
                              hipStream_t stream)
{
    const float* x   = (const float*)d_in[0];
    const int*   ei  = (const int*)  d_in[1];
    const float* ea  = (const float*)d_in[2];
    const float* W1  = (const float*)d_in[3];
    const float* b1  = (const float*)d_in[4];
    const float* gam = (const float*)d_in[5];
    const float* bet = (const float*)d_in[6];
    const float* W2  = (const float*)d_in[7];
    const float* b2  = (const float*)d_in[8];
    float* out = (float*)d_out;

    const int E = in_sizes[1] / 2;   // edge_index is [2, E]

    // d_out is poisoned 0xAA before every call — zero it for the scatter-add.
    hipMemsetAsync(d_out, 0, (size_t)out_size * sizeof(float), stream);

    const int block = 256;
    const int grid = (E + block - 1) / block;
    hipLaunchKernelGGL(mpconv_edge_kernel, dim3(grid), dim3(block), 0, stream,
                       x, ei, ea, W1, b1, gam, bet, W2, b2, out, E);
}

// Round 2
// 760.274 us; speedup vs baseline: 7.7620x; 7.7620x over previous
//
#include <hip/hip_runtime.h>
#include <math.h>

// ---------------------------------------------------------------------------
// MPConv round 2: bf16 MFMA for both GEMMs.
//  - prep kernel: W1[160,64],W2[64,64] f32 -> bf16 transposed [n][k] in d_ws
//  - main kernel: block = 4 waves, 256 edges. Per wave: 64 edges.
//      GEMM1: 4 Mtile x 4 Ntile x 5 Kstep mfma_f32_16x16x32_bf16
//      LN+GELU: shfl_xor reduce within 16-lane C-layout groups
//      H -> LDS (stride 72 bf16) -> A-frags for GEMM2 (2 Ksteps)
//      scatter: unsafeAtomicAdd per (edge, channel)  [unchanged this round]
// ---------------------------------------------------------------------------

using short8 = __attribute__((ext_vector_type(8))) short;
using f32x4  = __attribute__((ext_vector_type(4))) float;

#define LDH 72   // LDS stride for H tile, in bf16 elements (64+8 pad)

static __device__ __forceinline__ short f2bf(float f) {
    unsigned u = __float_as_uint(f);
    u += 0x7FFFu + ((u >> 16) & 1u);        // round-to-nearest-even
    return (short)(u >> 16);
}

static __device__ __forceinline__ short8 pack8(float4 a, float4 b) {
    short8 r;
    r[0] = f2bf(a.x); r[1] = f2bf(a.y); r[2] = f2bf(a.z); r[3] = f2bf(a.w);
    r[4] = f2bf(b.x); r[5] = f2bf(b.y); r[6] = f2bf(b.z); r[7] = f2bf(b.w);
    return r;
}

// ---- weight prep: f32 [k][n] -> bf16 [n][k] ------------------------------
__global__ void prep_weights(const float* __restrict__ W1,
                             const float* __restrict__ W2,
                             short* __restrict__ Wt1,   // [64][160]
                             short* __restrict__ Wt2)   // [64][64]
{
    int t = blockIdx.x * blockDim.x + threadIdx.x;
    if (t < 160 * 64) {
        int k = t / 64, n = t % 64;
        Wt1[n * 160 + k] = f2bf(W1[t]);
    }
    int t2 = t - 160 * 64;
    if (t2 >= 0 && t2 < 64 * 64) {
        int k = t2 / 64, n = t2 % 64;
        Wt2[n * 64 + k] = f2bf(W2[t2]);
    }
}

__global__ __launch_bounds__(256) void mpconv_mfma(
    const float* __restrict__ x,      // [N,64]
    const int*   __restrict__ ei,     // [2,E]
    const float* __restrict__ ea,     // [E,32]
    const short* __restrict__ Wt1,    // [64][160] bf16
    const float* __restrict__ b1,
    const float* __restrict__ gam,
    const float* __restrict__ bet,
    const short* __restrict__ Wt2,    // [64][64] bf16
    const float* __restrict__ b2,
    float*       __restrict__ out,    // [N,64]
    int E)
{
    __shared__ __align__(16) short Hlds[4][64][LDH];   // 36,864 B

    const int wave = threadIdx.x >> 6;
    const int lane = threadIdx.x & 63;
    const int g    = lane >> 4;        // quad id 0..3
    const int col  = lane & 15;
    const int eb   = blockIdx.x * 256 + wave * 64;     // wave's edge base

    // edges whose A-rows this lane loads (row m = col in each 16-row M tile)
    int aedge[4], ii[4], jj[4];
#pragma unroll
    for (int mt = 0; mt < 4; mt++) {
        int e = eb + mt * 16 + col;
        e = (e < E) ? e : (E - 1);     // clamp; invalid rows skipped at scatter
        aedge[mt] = e;
        ii[mt] = ei[e];
        jj[mt] = ei[E + e];
    }

    // per-lane channel params for its 4 columns (col + 16*nt)
    float b1c[4], gc[4], bc[4], b2c[4];
#pragma unroll
    for (int nt = 0; nt < 4; nt++) {
        int c = col + 16 * nt;
        b1c[nt] = b1[c]; gc[nt] = gam[c]; bc[nt] = bet[c]; b2c[nt] = b2[c];
    }

    // ---- GEMM1: [64,160] @ [160,64] -----------------------------------
    f32x4 acc[4][4];
#pragma unroll
    for (int mt = 0; mt < 4; mt++)
#pragma unroll
        for (int nt = 0; nt < 4; nt++)
            acc[mt][nt] = (f32x4){0.f, 0.f, 0.f, 0.f};

#pragma unroll
    for (int ks = 0; ks < 5; ks++) {
        const int k0 = ks * 32;
        const int kk = k0 + g * 8;     // this quad's k-chunk (8 wide)

        short8 afrag[4];
#pragma unroll
        for (int mt = 0; mt < 4; mt++) {
            const float* s;
            if (k0 < 64)       s = x  + (size_t)ii[mt] * 64 + kk;
            else if (k0 < 128) s = x  + (size_t)jj[mt] * 64 + (kk - 64);
            else               s = ea + (size_t)aedge[mt] * 32 + (kk - 128);
            float4 a = *(const float4*)s;
            float4 b = *(const float4*)(s + 4);
            afrag[mt] = pack8(a, b);
        }
        short8 bfrag[4];
#pragma unroll
        for (int nt = 0; nt < 4; nt++)
            bfrag[nt] = *(const short8*)(Wt1 + (size_t)(col + 16 * nt) * 160 + kk);

#pragma unroll
        for (int mt = 0; mt < 4; mt++)
#pragma unroll
            for (int nt = 0; nt < 4; nt++)
                acc[mt][nt] = __builtin_amdgcn_mfma_f32_16x16x32_bf16(
                    afrag[mt], bfrag[nt], acc[mt][nt], 0, 0, 0);
    }

    // ---- +b1, LayerNorm, GELU, write H to LDS -------------------------
    // C layout: row = g*4 + r, col = col + 16*nt  (within each 16x16 tile)
#pragma unroll
    for (int mt = 0; mt < 4; mt++) {
        float s[4] = {0.f, 0.f, 0.f, 0.f};
        float q[4] = {0.f, 0.f, 0.f, 0.f};
#pragma unroll
        for (int nt = 0; nt < 4; nt++) {
#pragma unroll
            for (int r = 0; r < 4; r++) {
                float v = acc[mt][nt][r] + b1c[nt];
                acc[mt][nt][r] = v;
                s[r] += v;
                q[r] += v * v;
            }
        }
#pragma unroll
        for (int m = 1; m < 16; m <<= 1) {
#pragma unroll
            for (int r = 0; r < 4; r++) {
                s[r] += __shfl_xor(s[r], m);
                q[r] += __shfl_xor(q[r], m);
            }
        }
#pragma unroll
        for (int r = 0; r < 4; r++) {
            float mu  = s[r] * (1.0f / 64.0f);
            float var = q[r] * (1.0f / 64.0f) - mu * mu;
            float inv = rsqrtf(var + 1e-5f);
            int row = mt * 16 + g * 4 + r;
#pragma unroll
            for (int nt = 0; nt < 4; nt++) {
                float h = (acc[mt][nt][r] - mu) * inv * gc[nt] + bc[nt];
                h = 0.5f * h * (1.0f + erff(h * 0.70710678118654752f));
                Hlds[wave][row][col + 16 * nt] = f2bf(h);
            }
        }
    }
    __syncthreads();

    // ---- GEMM2: [64,64] @ [64,64] -------------------------------------
    f32x4 acc2[4][4];
#pragma unroll
    for (int mt = 0; mt < 4; mt++)
#pragma unroll
        for (int nt = 0; nt < 4; nt++)
            acc2[mt][nt] = (f32x4){0.f, 0.f, 0.f, 0.f};

#pragma unroll
    for (int ks = 0; ks < 2; ks++) {
        const int kk = ks * 32 + g * 8;
        short8 af[4], bf[4];
#pragma unroll
        for (int mt = 0; mt < 4; mt++)
            af[mt] = *(const short8*)&Hlds[wave][mt * 16 + col][kk];
#pragma unroll
        for (int nt = 0; nt < 4; nt++)
            bf[nt] = *(const short8*)(Wt2 + (size_t)(col + 16 * nt) * 64 + kk);
#pragma unroll
        for (int mt = 0; mt < 4; mt++)
#pragma unroll
            for (int nt = 0; nt < 4; nt++)
                acc2[mt][nt] = __builtin_amdgcn_mfma_f32_16x16x32_bf16(
                    af[mt], bf[nt], acc2[mt][nt], 0, 0, 0);
    }

    // ---- +b2 and scatter-add to out[j] --------------------------------
#pragma unroll
    for (int mt = 0; mt < 4; mt++) {
#pragma unroll
        for (int r = 0; r < 4; r++) {
            int e = eb + mt * 16 + g * 4 + r;
            if (e < E) {
                int dst = ei[E + e];           // wave-uniform per 16-lane group
                float* op = out + (size_t)dst * 64 + col;
#pragma unroll
                for (int nt = 0; nt < 4; nt++)
                    unsafeAtomicAdd(op + 16 * nt, acc2[mt][nt][r] + b2c[nt]);
            }
        }
    }
}

extern "C" void kernel_launch(void* const* d_in, const int* in_sizes, int n_in,
                              void* d_out, int out_size, void* d_ws, size_t ws_size,
                              hipStream_t stream)
{
    const float* x   = (const float*)d_in[0];
    const int*   ei  = (const int*)  d_in[1];
    const float* ea  = (const float*)d_in[2];
    const float* W1  = (const float*)d_in[3];
    const float* b1  = (const float*)d_in[4];
    const float* gam = (const float*)d_in[5];
    const float* bet = (const float*)d_in[6];
    const float* W2  = (const float*)d_in[7];
    const float* b2  = (const float*)d_in[8];
    float* out = (float*)d_out;

    const int E = in_sizes[1] / 2;

    // workspace: Wt1 bf16 [64][160] then Wt2 bf16 [64][64]
    short* Wt1 = (short*)d_ws;
    short* Wt2 = Wt1 + 160 * 64;

    hipMemsetAsync(d_out, 0, (size_t)out_size * sizeof(float), stream);

    {
        int total = 160 * 64 + 64 * 64;
        int grid = (total + 255) / 256;
        hipLaunchKernelGGL(prep_weights, dim3(grid), dim3(256), 0, stream,
                           W1, W2, Wt1, Wt2);
    }
    {
        int grid = (E + 255) / 256;
        hipLaunchKernelGGL(mpconv_mfma, dim3(grid), dim3(256), 0, stream,
                           x, ei, ea, Wt1, b1, gam, bet, Wt2, b2, out, E);
    }
}